// Round 3
// baseline (467.955 us; speedup 1.0000x reference)
//
#include <hip/hip_runtime.h>

#define Bn   32
#define Cn   17
#define Hn   96
#define Wn   72
#define Kn   3
#define KKn  9
#define PADn 1
#define HWn  (Hn * Wn)            // 6912
#define TPB  192                  // 3 waves/block -> clean occupancy quantization
#define NPX  4                    // consecutive pixels/thread -> dwordx4 loads
#define CHUNK (TPB * NPX)         // 768 px
#define NCHUNK 3                  // chunks per block -> 2304 px = 32 rows
#define ROWS_PER_BLOCK 32
#define NBLK_X (Hn / ROWS_PER_BLOCK)   // 3

// padded LDS image: rows -1..97 (99), cols -1..73 (75); index (y+1)*75 + (x+1)
#define PSTR 75
#define PROWS 99
#define XS_SIZE (PROWS * PSTR)    // 7425 floats = 29.7 KB -> 5 blocks/CU by LDS

typedef float f4 __attribute__((ext_vector_type(4)));

// __launch_bounds__(192, 4): 4 waves/EU min -> VGPR capped at 128 ->
// wave budget 16/CU -> blocks/CU = min(LDS:5, 16/3=5) = 5 -> 15 waves/CU.
__global__ __launch_bounds__(TPB, 4) void deform_conv_kernel(
    const float* __restrict__ x,
    const float* __restrict__ offsets,
    const float* __restrict__ mask,
    const float* __restrict__ weight,
    const float* __restrict__ bias,
    float* __restrict__ out)
{
    __shared__ float xs[XS_SIZE];

    const int tid = threadIdx.x;
    const int bc  = blockIdx.y;              // b*C + c
    const int c   = bc % Cn;

    // ---- zero ONLY the guard border (interior fully overwritten below) ----
    // guards: full rows 0,97,98 (3*75=225) + cols {0,73,74} of rows 1..96 (288) = 513
    for (int g = tid; g < 513; g += TPB) {
        int r, cc;
        if (g < 225) {
            r  = (g < 75) ? 0 : ((g < 150) ? 97 : 98);
            cc = g % 75;
        } else {
            const int i = g - 225;
            r  = 1 + i / 3;
            const int j = i % 3;
            cc = (j == 0) ? 0 : (72 + j);
        }
        xs[r * PSTR + cc] = 0.f;
    }

    // ---- stage interior once (dwordx4; 72%4==0 so chunks stay in-row) ----
    {
        const f4* __restrict__ xp4 = (const f4*)(x + (size_t)bc * HWn);
        #pragma unroll
        for (int j = 0; j < HWn / 4 / TPB; ++j) {   // 9 iters
            const int ci  = j * TPB + tid;
            const f4 v = xp4[ci];
            const int idx = ci * 4;
            const int y = idx / Wn;
            const int xcol = idx - y * Wn;
            float* d = &xs[(y + 1) * PSTR + (xcol + 1)];
            d[0] = v.x; d[1] = v.y; d[2] = v.z; d[3] = v.w;
        }
    }
    __syncthreads();

    const float* __restrict__ offp = offsets + (size_t)bc * (KKn * 2 * HWn);
    const float* __restrict__ mp   = mask    + (size_t)bc * (KKn * HWn);
    const float* __restrict__ wp   = weight  + c * KKn;   // block-uniform -> scalar
    const float bv = bias[c];
    const size_t ob = (size_t)bc * HWn;

    // ---- 3 chunks of 768 px; LDS image is read-only so no barriers between ----
    #pragma unroll 1
    for (int ch = 0; ch < NCHUNK; ++ch) {
        const int hw0 = blockIdx.x * (CHUNK * NCHUNK) + ch * CHUNK + tid * NPX;
        const int h   = hw0 / Wn;            // all 4 px share this row
        const int w0  = hw0 - h * Wn;        // multiple of 4

        float acc[NPX] = {bv, bv, bv, bv};
        const float hf  = (float)h;
        const float wf0 = (float)w0;

        #pragma unroll
        for (int kk = 0; kk < KKn; ++kk) {
            const float wk  = wp[kk];
            const int   ky  = kk / Kn;
            const int   kx  = kk - ky * Kn;
            const float kyo = (float)(ky - PADn);
            const float kxo = (float)(kx - PADn);

            const f4 dy4 = __builtin_nontemporal_load(
                (const f4*)(offp + (size_t)(kk * 2 + 0) * HWn + hw0));
            const f4 dx4 = __builtin_nontemporal_load(
                (const f4*)(offp + (size_t)(kk * 2 + 1) * HWn + hw0));
            const f4 m4  = __builtin_nontemporal_load(
                (const f4*)(mp + (size_t)kk * HWn + hw0));

            const float dyv[NPX] = {dy4.x, dy4.y, dy4.z, dy4.w};
            const float dxv[NPX] = {dx4.x, dx4.y, dx4.z, dx4.w};
            const float mv [NPX] = {m4.x,  m4.y,  m4.z,  m4.w};

            const float hk = hf + kyo;

            #pragma unroll
            for (int p = 0; p < NPX; ++p) {
                // clamp to [-1,H]/[-1,W]: outside that the contribution is exactly 0;
                // at the clamp point the surviving corner weight is 0 (guard zeros
                // absorb the invalid corners).
                float py = hk + dyv[p];
                float px = wf0 + ((float)p + kxo) + dxv[p];
                py = fminf(fmaxf(py, -1.f), (float)Hn);
                px = fminf(fmaxf(px, -1.f), (float)Wn);

                const float y0f = floorf(py);
                const float x0f = floorf(px);
                const float wy  = py - y0f;
                const float wx  = px - x0f;
                const int y0 = (int)y0f;                 // in [-1, 96]
                const int x0 = (int)x0f;                 // in [-1, 72]

                const float* pr = &xs[(y0 + 1) * PSTR + (x0 + 1)];
                const float v00 = pr[0];
                const float v01 = pr[1];
                const float v10 = pr[PSTR];
                const float v11 = pr[PSTR + 1];

                const float top = v00 + wx * (v01 - v00);
                const float bot = v10 + wx * (v11 - v10);
                const float v   = top + wy * (bot - top);

                acc[p] += v * (mv[p] * wk);
            }
        }

        f4 o;
        o.x = acc[0]; o.y = acc[1]; o.z = acc[2]; o.w = acc[3];
        __builtin_nontemporal_store(o, (f4*)(out + ob + hw0));
    }
}

extern "C" void kernel_launch(void* const* d_in, const int* in_sizes, int n_in,
                              void* d_out, int out_size, void* d_ws, size_t ws_size,
                              hipStream_t stream) {
    const float* x       = (const float*)d_in[0];
    const float* offsets = (const float*)d_in[1];
    const float* mask    = (const float*)d_in[2];
    const float* weight  = (const float*)d_in[3];
    const float* bias    = (const float*)d_in[4];
    float* out = (float*)d_out;

    dim3 block(TPB, 1, 1);
    dim3 grid(NBLK_X, Bn * Cn, 1);
    deform_conv_kernel<<<grid, block, 0, stream>>>(x, offsets, mask, weight, bias, out);
}

// Round 4
// 434.383 us; speedup vs baseline: 1.0773x; 1.0773x over previous
//
#include <hip/hip_runtime.h>

#define Bn   32
#define Cn   17
#define Hn   96
#define Wn   72
#define Kn   3
#define KKn  9
#define PADn 1
#define HWn  (Hn * Wn)            // 6912
#define TPB  576                  // 9 waves
#define NPX  2                    // 2 consecutive px/thread -> dwordx2 loads, stride-2 lanes
#define CHUNK (TPB * NPX)         // 1152 px = 16 rows
#define NBLK_X (HWn / CHUNK)      // 6

// padded LDS image: rows -1..97 (99), cols -1..73 (75); index (y+1)*75 + (x+1)
#define PSTR 75
#define PROWS 99
#define XS_SIZE (PROWS * PSTR)    // 7425 floats = 29.7 KB -> 5 blocks/CU by LDS

typedef float f4 __attribute__((ext_vector_type(4)));
typedef float f2 __attribute__((ext_vector_type(2)));

__global__ __launch_bounds__(TPB) void deform_conv_kernel(
    const float* __restrict__ x,
    const float* __restrict__ offsets,
    const float* __restrict__ mask,
    const float* __restrict__ weight,
    const float* __restrict__ bias,
    float* __restrict__ out)
{
    __shared__ float xs[XS_SIZE];

    const int tid = threadIdx.x;
    const int bc  = blockIdx.y;              // b*C + c
    const int c   = bc % Cn;

    // ---- zero ONLY the guard border (interior fully overwritten below) ----
    // guards: full rows 0,97,98 (3*75=225) + cols {0,73,74} of rows 1..96 (288) = 513
    if (tid < 225) {
        const int r  = (tid < 75) ? 0 : ((tid < 150) ? 97 : 98);
        xs[r * PSTR + (tid % 75)] = 0.f;
    } else if (tid < 513) {
        const int i  = tid - 225;
        const int r  = 1 + i / 3;            // 1..96
        const int j  = i % 3;
        const int cc = (j == 0) ? 0 : (72 + j);   // 0, 73, 74
        xs[r * PSTR + cc] = 0.f;
    }

    // ---- stage full interior (dwordx4; 72%4==0 so chunks stay in-row) ----
    {
        const f4* __restrict__ xp4 = (const f4*)(x + (size_t)bc * HWn);
        #pragma unroll
        for (int j = 0; j < HWn / 4 / TPB; ++j) {   // 3 iters
            const int ci  = j * TPB + tid;
            const f4 v = xp4[ci];
            const int idx = ci * 4;
            const int y = idx / Wn;
            const int xcol = idx - y * Wn;
            float* d = &xs[(y + 1) * PSTR + (xcol + 1)];
            d[0] = v.x; d[1] = v.y; d[2] = v.z; d[3] = v.w;
        }
    }
    __syncthreads();

    // ---- thread map: 2 CONSECUTIVE pixels per thread (same image row) ----
    const int hw0 = blockIdx.x * CHUNK + tid * NPX;
    const int h   = hw0 / Wn;                // both px share this row (hw0 even, w0<=70)
    const int w0  = hw0 - h * Wn;            // even

    const float* __restrict__ offp = offsets + (size_t)bc * (KKn * 2 * HWn);
    const float* __restrict__ mp   = mask    + (size_t)bc * (KKn * HWn);
    const float* __restrict__ wp   = weight  + c * KKn;   // block-uniform -> scalar

    const float bv = bias[c];
    float acc[NPX] = {bv, bv};

    const float hf  = (float)h;
    const float wf0 = (float)w0;

    #pragma unroll
    for (int kk = 0; kk < KKn; ++kk) {
        const float wk  = wp[kk];
        const int   ky  = kk / Kn;
        const int   kx  = kk - ky * Kn;
        const float kyo = (float)(ky - PADn);
        const float kxo = (float)(kx - PADn);

        // one dwordx2 per stream per kk (512 B/wave/instr, coalesced, nt hint)
        const f2 dy2 = __builtin_nontemporal_load(
            (const f2*)(offp + (size_t)(kk * 2 + 0) * HWn + hw0));
        const f2 dx2 = __builtin_nontemporal_load(
            (const f2*)(offp + (size_t)(kk * 2 + 1) * HWn + hw0));
        const f2 m2  = __builtin_nontemporal_load(
            (const f2*)(mp + (size_t)kk * HWn + hw0));

        const float dyv[NPX] = {dy2.x, dy2.y};
        const float dxv[NPX] = {dx2.x, dx2.y};
        const float mv [NPX] = {m2.x,  m2.y};

        const float hk = hf + kyo;

        #pragma unroll
        for (int p = 0; p < NPX; ++p) {
            // clamp to [-1,H]/[-1,W]: outside that the contribution is exactly 0;
            // at the clamp point the surviving corner weight is 0 (guard zeros
            // absorb the invalid corners).
            float py = hk + dyv[p];
            float px = wf0 + ((float)p + kxo) + dxv[p];
            py = fminf(fmaxf(py, -1.f), (float)Hn);
            px = fminf(fmaxf(px, -1.f), (float)Wn);

            const float y0f = floorf(py);
            const float x0f = floorf(px);
            const float wy  = py - y0f;
            const float wx  = px - x0f;
            const int y0 = (int)y0f;                 // in [-1, 96]
            const int x0 = (int)x0f;                 // in [-1, 72]

            const float* pr = &xs[(y0 + 1) * PSTR + (x0 + 1)];
            const float v00 = pr[0];
            const float v01 = pr[1];
            const float v10 = pr[PSTR];
            const float v11 = pr[PSTR + 1];

            const float top = v00 + wx * (v01 - v00);
            const float bot = v10 + wx * (v11 - v10);
            const float v   = top + wy * (bot - top);

            acc[p] += v * (mv[p] * wk);
        }
    }

    // ---- one dwordx2 store (hw0 even -> 8B aligned) ----
    f2 o;
    o.x = acc[0]; o.y = acc[1];
    __builtin_nontemporal_store(o, (f2*)(out + (size_t)bc * HWn + hw0));
}

extern "C" void kernel_launch(void* const* d_in, const int* in_sizes, int n_in,
                              void* d_out, int out_size, void* d_ws, size_t ws_size,
                              hipStream_t stream) {
    const float* x       = (const float*)d_in[0];
    const float* offsets = (const float*)d_in[1];
    const float* mask    = (const float*)d_in[2];
    const float* weight  = (const float*)d_in[3];
    const float* bias    = (const float*)d_in[4];
    float* out = (float*)d_out;

    dim3 block(TPB, 1, 1);
    dim3 grid(NBLK_X, Bn * Cn, 1);
    deform_conv_kernel<<<grid, block, 0, stream>>>(x, offsets, mask, weight, bias, out);
}